// Round 18
// baseline (454.196 us; speedup 1.0000x reference)
//
#include <hip/hip_runtime.h>
#include <hip/hip_bf16.h>
#include <hip/hip_fp16.h>
#include <math.h>

#define B_ 16
#define IN_DIM_ 4096
#define D_ 100
#define H_ 200
#define L_ 4
#define N_ (B_*IN_DIM_)     // 65536
#define E_ (8*B_*IN_DIM_)   // 524288
#define EPS_ 1e-7f

typedef __attribute__((ext_vector_type(8))) short bf16x8s;  // 8 bf16 (4 VGPRs)
typedef __attribute__((ext_vector_type(4))) float f32x4;

__device__ inline unsigned pack_bf16x2(float a, float b){
  __hip_bfloat16 x = __float2bfloat16(a), y = __float2bfloat16(b);
  unsigned short ux = *(unsigned short*)&x, uy = *(unsigned short*)&y;
  return (unsigned)ux | ((unsigned)uy << 16);
}
__device__ inline __half2 u2h(unsigned v){ return *(__half2*)&v; }

// fp8 e4m3 (OCP on gfx950) encode via HW cvt
__device__ inline unsigned char f2fp8(float v){
  unsigned p = __builtin_amdgcn_cvt_pk_fp8_f32(v, 0.f, 0u, false);
  return (unsigned char)(p & 0xFF);
}

// ====== enc LN closed-form stats: h=x*w+b (rank-1+bias) => 5 scalars ========
__global__ void enc_stats_kernel(const float* __restrict__ enc_w,
                                 const float* __restrict__ enc_b,
                                 float* __restrict__ stats) {
  __shared__ float sw[128], sb[128], sww[128], swb[128], sbb[128];
  int t = threadIdx.x;
  float w=0.f, b=0.f;
  if (t < D_){ w = enc_w[t]; b = enc_b[t]; }
  sw[t]=w; sb[t]=b; sww[t]=w*w; swb[t]=w*b; sbb[t]=b*b;
  __syncthreads();
  for (int off=64; off; off>>=1){
    if (t<off){ sw[t]+=sw[t+off]; sb[t]+=sb[t+off]; sww[t]+=sww[t+off];
                swb[t]+=swb[t+off]; sbb[t]+=sbb[t+off]; }
    __syncthreads();
  }
  if (t==0){
    float mw = sw[0]*(1.f/D_), mb = sb[0]*(1.f/D_);
    stats[0]=mw; stats[1]=mb;
    stats[2]=sww[0]*(1.f/D_) - mw*mw;      // Var_w
    stats[3]=swb[0]*(1.f/D_) - mw*mb;      // Cov_wb
    stats[4]=sbb[0]*(1.f/D_) - mb*mb;      // Var_b
  }
}

// ================= merged setup: dense1 | enc_ln | deg | prep ================
#define D1_BLKS_   512
#define ENC_BLKS_  2048
#define DEG_BLKS_  2048
#define PREP_BLKS_ 448
#define SETUP_BLKS_ (D1_BLKS_+ENC_BLKS_+DEG_BLKS_+PREP_BLKS_)

__global__ void setup_kernel(const float* __restrict__ x, const float* __restrict__ enc_w,
                             const float* __restrict__ enc_b, const float* __restrict__ g0,
                             const float* __restrict__ b0, const float* __restrict__ stats,
                             __half* __restrict__ h, char* __restrict__ hnb,
                             char* __restrict__ hnb8,
                             const int* __restrict__ dsts, int* __restrict__ deg,
                             const float* __restrict__ h1_w, float* __restrict__ xs1acc,
                             const float* __restrict__ w1, const float* __restrict__ w2,
                             __hip_bfloat16* __restrict__ w1T, __hip_bfloat16* __restrict__ w2T) {
  __shared__ float xl[16][32];    // 2KB (dense1 only)
  int bid = blockIdx.x;
  int t = threadIdx.x;
  if (bid < D1_BLKS_) {
    int bx = bid & 3, by = bid >> 2;
    int k0 = by * 32;
    for (int i = t; i < 16*32; i += 256) {
      int b = i >> 5, kk = i & 31;
      xl[b][kk] = x[b*IN_DIM_ + k0 + kk];
    }
    __syncthreads();
    int c = bx*256 + t;
    if (c >= 1000) return;
    float acc[B_];
    #pragma unroll
    for (int b=0;b<B_;b++) acc[b]=0.f;
    #pragma unroll 4
    for (int kk=0; kk<32; kk++) {
      float w = h1_w[(size_t)(k0+kk)*1000 + c];
      #pragma unroll
      for (int b=0;b<B_;b++) acc[b] += xl[b][kk]*w;
    }
    #pragma unroll
    for (int b=0;b<B_;b++) atomicAdd(&xs1acc[b*1000+c], acc[b]);
  } else if (bid < D1_BLKS_+ENC_BLKS_) {
    int eb = bid - D1_BLKS_;
    int wave = t >> 6, lane = t & 63;
    int base = eb*32 + wave*8;              // this wave's 8 consecutive nodes
    float mw = stats[0], mb = stats[1], vw = stats[2], cwb = stats[3], vb = stats[4];
    float xv = 0.f;
    if (lane < 8) xv = x[base + lane];
    int c0 = 2*lane, c1 = c0+1;
    bool v = c0 < D_;
    float ew0=0.f, ew1=0.f, ebv0=0.f, ebv1=0.f, gg0=0.f, gg1=0.f, bv0=0.f, bv1=0.f;
    if (v) { ew0=enc_w[c0]; ew1=enc_w[c1]; ebv0=enc_b[c0]; ebv1=enc_b[c1];
             gg0=g0[c0]; gg1=g0[c1]; bv0=b0[c0]; bv1=b0[c1]; }
    #pragma unroll
    for (int it=0; it<8; ++it) {
      int wid = base + it;
      float xn = __shfl(xv, it, 64);
      float mu = fmaf(xn, mw, mb);
      float var = fmaf(xn*xn, vw, fmaf(2.f*xn, cwb, vb));
      float rstd = rsqrtf(var + 1e-5f);
      float h0 = fmaf(xn, ew0, ebv0);
      float h1 = fmaf(xn, ew1, ebv1);
      if (c0 < 112) *(__half2*)&h[(size_t)wid*112 + c0] = __floats2half2_rn(h0, h1);
      float n0 = v? fmaxf(fmaf((h0-mu)*rstd, gg0, bv0), 0.f) : 0.f;
      float n1 = v? fmaxf(fmaf((h1-mu)*rstd, gg1, bv1), 0.f) : 0.f;
      *(__half2*)(hnb + (size_t)wid*256 + 4*lane) = __floats2half2_rn(n0, n1);
      unsigned short p8 = (unsigned short)f2fp8(n0) | ((unsigned short)f2fp8(n1) << 8);
      *(unsigned short*)(hnb8 + (size_t)wid*128 + c0) = p8;
    }
  } else if (bid < D1_BLKS_+ENC_BLKS_+DEG_BLKS_) {
    int e = (bid - (D1_BLKS_+ENC_BLKS_))*256 + t;
    if (e < E_) atomicAdd(&deg[dsts[e]], 1);
  } else {
    int idx = (bid - (D1_BLKS_+ENC_BLKS_+DEG_BLKS_))*256 + t;
    if (idx < L_*224*128) {
      int l = idx / (224*128);
      int rem = idx % (224*128);
      int col = rem / 128, k = rem % 128;
      float v = (col < H_ && k < D_) ? w1[(l*D_ + k)*H_ + col] : 0.f;
      w1T[idx] = __float2bfloat16(v);
    }
    if (idx < L_*112*224) {
      int l = idx / (112*224);
      int rem = idx % (112*224);
      int col = rem / 224, k = rem % 224;
      float v = (col < D_ && k < H_) ? w2[(l*H_ + k)*D_ + col] : 0.f;
      w2T[idx] = __float2bfloat16(v);
    }
  }
}

// ====== stage2: scan (blk 0) | dense2 (blk 1-4) | degree hist (blk 5-8) =====
__global__ void stage2_kernel(const int* __restrict__ deg, int* __restrict__ row_start,
                              const float* __restrict__ xs1acc, const float* __restrict__ h1_b,
                              const float* __restrict__ h2_w, float* __restrict__ xs2acc,
                              int* __restrict__ hist) {
  __shared__ int sums[1024];
  int t = threadIdx.x;
  int bid = blockIdx.x;
  if (bid == 0) {
    int base = t*64;
    int s = 0;
    for (int j=0;j<64;j++) s += deg[base+j];
    sums[t] = s;
    __syncthreads();
    for (int off=1; off<1024; off<<=1){
      int add = (t>=off)? sums[t-off] : 0;
      __syncthreads();
      sums[t] += add;
      __syncthreads();
    }
    int excl = (t==0)? 0 : sums[t-1];
    int run = excl;
    for (int j=0;j<64;j++){ row_start[base+j] = run; run += deg[base+j]; }
    if (t==1023) row_start[N_] = run;
  } else if (bid <= 4) {
    int T = (bid-1)*1024 + t;
    if (T >= 100*40) return;
    int c = T % 100, kc = T / 100;
    int k0 = kc*25;
    float acc[B_];
    #pragma unroll
    for (int b=0;b<B_;b++) acc[b]=0.f;
    for (int kk=0;kk<25;kk++){
      int k = k0+kk;
      float w = h2_w[k*100 + c];
      float bk = h1_b[k];
      #pragma unroll
      for (int b=0;b<B_;b++){
        float m = xs1acc[b*1000+k] + bk;
        m = (m>0.f)? m : 0.01f*m;
        acc[b] += m*w;
      }
    }
    #pragma unroll
    for (int b=0;b<B_;b++) atomicAdd(&xs2acc[b*100+c], acc[b]);
  } else {
    __shared__ int lh[256];
    if (t < 256) lh[t] = 0;
    __syncthreads();
    int base = (bid-5)*16384;
    for (int n = base + t; n < base + 16384; n += 1024) {
      int d = deg[n]; if (d > 255) d = 255;
      atomicAdd(&lh[d], 1);
    }
    __syncthreads();
    if (t < 256 && lh[t] > 0) atomicAdd(&hist[t], lh[t]);
  }
}

// ====== binscan: exclusive prefix over 256 degree bins; zero bincnt =========
__global__ void binscan_kernel(const int* __restrict__ hist, int* __restrict__ binoff,
                               int* __restrict__ bincnt) {
  __shared__ int s[256];
  int t = threadIdx.x;
  int hv = hist[t];
  s[t] = hv;
  __syncthreads();
  for (int off=1; off<256; off<<=1){
    int v = (t>=off)? s[t-off] : 0;
    __syncthreads();
    s[t] += v;
    __syncthreads();
  }
  binoff[t] = s[t] - hv;   // exclusive prefix
  bincnt[t] = 0;
}

// ====== scatter: edges (blk<2048) | node order by degree (blk>=2048) ========
__global__ void scatter_kernel(const int* __restrict__ srcs, const int* __restrict__ dst,
                               const int* __restrict__ row_start, int* __restrict__ cnt,
                               int* __restrict__ sorted_src,
                               const int* __restrict__ deg, const int* __restrict__ binoff,
                               int* __restrict__ bincnt, int* __restrict__ order) {
  int bid = blockIdx.x;
  int t = threadIdx.x;
  if (bid < 2048) {
    int e = bid*256 + t;
    int d = dst[e];
    int p = row_start[d] + atomicAdd(&cnt[d], 1);
    sorted_src[p] = srcs[e];
  } else {
    __shared__ int lh[256], lbase[256];
    int n = (bid-2048)*256 + t;
    int d = deg[n]; int b = (d > 255) ? 255 : d;
    lh[t] = 0;
    __syncthreads();
    int myrank = atomicAdd(&lh[b], 1);
    __syncthreads();
    lbase[t] = (lh[t] > 0) ? atomicAdd(&bincnt[t], lh[t]) : 0;
    __syncthreads();
    order[binoff[b] + lbase[b] + myrank] = n;
  }
}

// ---------------- softmax aggregation: 2 nodes/wave, fp8, degree-sorted -----
__global__ void agg_kernel(const char* __restrict__ hnb, const char* __restrict__ hnb8,
                           const int* __restrict__ row_start,
                           const int* __restrict__ sorted_src,
                           const int* __restrict__ order, unsigned* __restrict__ u) {
  int gw = (blockIdx.x*256 + threadIdx.x) >> 6;   // wave id: 0..N/2-1
  int lane = threadIdx.x & 63;
  int lpos = lane & 31;
  int gbase = lane & 32;                          // 0 or 32: group base lane
  int node = order[gw*2 + (lane >> 5)];
  int beg = row_start[node];
  int deg = row_start[node+1] - beg;
  int dother = __shfl_xor(deg, 32, 64);           // other group's (uniform) deg
  int mdeg = deg > dother ? deg : dother;
  const char* lanep8 = hnb8 + 4*lpos;
  float s0=0.f,s1=0.f,s2=0.f,s3=0.f, w0=0.f,w1=0.f,w2=0.f,w3=0.f;

#define CONSUME_(R) { \
    float v0=__builtin_amdgcn_cvt_f32_fp8(R,0)+EPS_; \
    float v1=__builtin_amdgcn_cvt_f32_fp8(R,1)+EPS_; \
    float v2=__builtin_amdgcn_cvt_f32_fp8(R,2)+EPS_; \
    float v3=__builtin_amdgcn_cvt_f32_fp8(R,3)+EPS_; \
    float e0=__expf(v0), e1=__expf(v1), e2=__expf(v2), e3=__expf(v3); \
    s0+=e0; w0=fmaf(e0,v0,w0); s1+=e1; w1=fmaf(e1,v1,w1); \
    s2+=e2; w2=fmaf(e2,v2,w2); s3+=e3; w3=fmaf(e3,v3,w3); }

  for (int cb=0; cb<mdeg; cb+=32){
    int cidx = (cb + lpos < deg) ? sorted_src[beg + cb + lpos] : 0;
    int cnt = mdeg - cb; if (cnt > 32) cnt = 32;          // wave-uniform
    int grem = deg - cb;                                   // per-group remaining
    int glim = grem < cnt ? grem : cnt; if (glim < 0) glim = 0;
    unsigned r0=0, r1=0, r2=0, r3=0;
    if (0 < glim) r0 = *(const unsigned*)(lanep8 + (size_t)__shfl(cidx, gbase+0)*128);
    if (1 < glim) r1 = *(const unsigned*)(lanep8 + (size_t)__shfl(cidx, gbase+1)*128);
    if (2 < glim) r2 = *(const unsigned*)(lanep8 + (size_t)__shfl(cidx, gbase+2)*128);
    if (3 < glim) r3 = *(const unsigned*)(lanep8 + (size_t)__shfl(cidx, gbase+3)*128);
    for (int j=0; j<cnt; j+=4){
      unsigned n0=0, n1=0, n2=0, n3=0;
      if (j+4 < glim) n0 = *(const unsigned*)(lanep8 + (size_t)__shfl(cidx, gbase+j+4)*128);
      if (j+5 < glim) n1 = *(const unsigned*)(lanep8 + (size_t)__shfl(cidx, gbase+j+5)*128);
      if (j+6 < glim) n2 = *(const unsigned*)(lanep8 + (size_t)__shfl(cidx, gbase+j+6)*128);
      if (j+7 < glim) n3 = *(const unsigned*)(lanep8 + (size_t)__shfl(cidx, gbase+j+7)*128);
      if (j   < glim) CONSUME_(r0);
      if (j+1 < glim) CONSUME_(r1);
      if (j+2 < glim) CONSUME_(r2);
      if (j+3 < glim) CONSUME_(r3);
      r0=n0; r1=n1; r2=n2; r3=n3;
    }
  }
#undef CONSUME_

  uint2 own = *(const uint2*)(hnb + (size_t)node*256 + 8*lpos);
  __half2 oa = u2h(own.x), ob = u2h(own.y);
  float u0 = ((deg>0)? w0/s0 : 0.f) + __low2float(oa);
  float u1 = ((deg>0)? w1/s1 : 0.f) + __high2float(oa);
  float u2 = ((deg>0)? w2/s2 : 0.f) + __low2float(ob);
  float u3 = ((deg>0)? w3/s3 : 0.f) + __high2float(ob);
  if (lpos >= 25) { u0=0.f; u1=0.f; u2=0.f; u3=0.f; }   // zero K-pad cols 100..127
  uint2 outv; outv.x = pack_bf16x2(u0,u1); outv.y = pack_bf16x2(u2,u3);
  *(uint2*)((char*)u + (size_t)node*256 + 8*lpos) = outv;
}

// ---------------- GEMM1: weights-only LDS, direct-global A; z out = fp8 -----
__global__ __launch_bounds__(256,4) void gemm1_kernel(
    const char* __restrict__ u, const __hip_bfloat16* __restrict__ w1T,
    const float* __restrict__ b1, const float* __restrict__ bng, const float* __restrict__ bnb,
    char* __restrict__ z8) {
  __shared__ __align__(16) char wL[112*272];    // 30464 B
  int bid = blockIdx.x;
  int half = bid & 1;
  size_t row0 = (size_t)(bid >> 1) * 64;
  int t = threadIdx.x;
  const char* wg = (const char*)w1T + (size_t)half*112*256;
  #pragma unroll
  for (int c = t; c < 1792; c += 256) {
    int r = c >> 4, sb = (c & 15) << 4;
    *(float4*)(wL + r*272 + sb) = *(const float4*)(wg + (size_t)r*256 + sb);
  }
  __syncthreads();
  int wave = t >> 6, lane = t & 63;
  int l15 = lane & 15;
  int kgb = (lane >> 4) << 4;
  int ar = wave*16 + l15;
  bf16x8s a[4];
  #pragma unroll
  for (int ks=0; ks<4; ks++)
    a[ks] = *(const bf16x8s*)(u + (row0 + ar)*256 + ks*64 + kgb);
  f32x4 acc[7];
  #pragma unroll
  for (int n=0;n<7;n++) acc[n] = (f32x4){0.f,0.f,0.f,0.f};
  #pragma unroll
  for (int ks=0; ks<4; ks++) {
    int kb = ks*64 + kgb;
    #pragma unroll
    for (int n=0;n<7;n++) {
      bf16x8s b = *(const bf16x8s*)(wL + (n*16 + l15)*272 + kb);
      acc[n] = __builtin_amdgcn_mfma_f32_16x16x32_bf16(a[ks], b, acc[n], 0, 0, 0);
    }
  }
  size_t rbase = row0 + wave*16 + ((lane>>4)<<2);
  #pragma unroll
  for (int n=0;n<7;n++) {
    int col = half*112 + n*16 + l15;
    float bias = (col < H_) ? b1[col] : 0.f;
    float g    = (col < H_) ? bng[col] : 0.f;
    float bb   = (col < H_) ? bnb[col] : 0.f;
    #pragma unroll
    for (int r=0;r<4;r++) {
      float v = fmaxf((acc[n][r] + bias)*g + bb, 0.f);
      if (col >= H_) v = 0.f;
      *(unsigned char*)(z8 + (rbase + r)*224 + col) = f2fp8(v);
    }
  }
}

// ---------------- GEMM2: weights-only LDS, fp8 A (cvt to bf16) --------------
// LAST=1 also runs the output head in the last-finishing block.
template<int LAST>
__global__ __launch_bounds__(256,3) void gemm2_kernel(
    const char* __restrict__ z8, const __hip_bfloat16* __restrict__ w2T,
    const float* __restrict__ b2, __half* __restrict__ h,
    const float* __restrict__ lng, const float* __restrict__ lnb,
    char* __restrict__ hnb, char* __restrict__ hnb8, float* __restrict__ pooled,
    int* __restrict__ done,
    const float* __restrict__ xs2acc, const float* __restrict__ h2_b,
    const float* __restrict__ dec_w, const float* __restrict__ dec_b,
    float* __restrict__ out) {
  __shared__ __align__(16) char wL[112*464];    // 51968 B
  int t = threadIdx.x;
  size_t row0 = (size_t)blockIdx.x * 64;
  const char* wg = (const char*)w2T;
  for (int c = t; c < 3136; c += 256) {
    int r = c / 28, sb = (c - r*28) << 4;
    *(float4*)(wL + r*464 + sb) = *(const float4*)(wg + (size_t)r*448 + sb);
  }
  __syncthreads();
  int wave = t >> 6, lane = t & 63;
  int l15 = lane & 15;
  int kgb = (lane >> 4) << 4;     // bf16 byte offset within K-32 step
  int ar = wave*16 + l15;
  // A fragments from fp8 z8 (224B rows): 8 fp8 per lane -> cvt to bf16
  bf16x8s a[7];
  {
    const char* zrow = z8 + (row0 + ar)*224;
    int g8 = (lane >> 4) << 3;    // fp8 byte offset (8B per lane)
    #pragma unroll
    for (int ks=0; ks<7; ks++) {
      uint2 p = *(const uint2*)(zrow + ks*32 + g8);
      float f0=__builtin_amdgcn_cvt_f32_fp8(p.x,0), f1=__builtin_amdgcn_cvt_f32_fp8(p.x,1);
      float f2=__builtin_amdgcn_cvt_f32_fp8(p.x,2), f3=__builtin_amdgcn_cvt_f32_fp8(p.x,3);
      float f4=__builtin_amdgcn_cvt_f32_fp8(p.y,0), f5=__builtin_amdgcn_cvt_f32_fp8(p.y,1);
      float f6=__builtin_amdgcn_cvt_f32_fp8(p.y,2), f7=__builtin_amdgcn_cvt_f32_fp8(p.y,3);
      uint4 q;
      q.x = pack_bf16x2(f0,f1); q.y = pack_bf16x2(f2,f3);
      q.z = pack_bf16x2(f4,f5); q.w = pack_bf16x2(f6,f7);
      a[ks] = *(bf16x8s*)&q;
    }
  }
  f32x4 acc[7];
  #pragma unroll
  for (int n=0;n<7;n++) acc[n] = (f32x4){0.f,0.f,0.f,0.f};
  #pragma unroll
  for (int ks=0; ks<7; ks++) {
    int kb = ks*64 + kgb;
    #pragma unroll
    for (int n=0;n<7;n++) {
      bf16x8s b = *(const bf16x8s*)(wL + (n*16 + l15)*464 + kb);
      acc[n] = __builtin_amdgcn_mfma_f32_16x16x32_bf16(a[ks], b, acc[n], 0, 0, 0);
    }
  }
  size_t rbase = row0 + wave*16 + ((lane>>4)<<2);

  float x_[7][4];
  float sum[4]  = {0,0,0,0};
  float sum2[4] = {0,0,0,0};
  float psum[7] = {0,0,0,0,0,0,0};
  #pragma unroll
  for (int n=0;n<7;n++) {
    int col = n*16 + l15;
    bool valid = col < D_;
    float bias = valid ? b2[col] : 0.f;
    #pragma unroll
    for (int r=0;r<4;r++) {
      float xv = 0.f;
      if (valid) xv = acc[n][r] + bias + __half2float(h[(rbase + r)*112 + col]);
      x_[n][r] = xv;
      if (LAST) {
        psum[n] += xv;
      } else {
        sum[r] += xv; sum2[r] += xv*xv;
        if (valid) h[(rbase + r)*112 + col] = __float2half(xv);
      }
    }
  }

  if (LAST) {
    #pragma unroll
    for (int n=0;n<7;n++) {
      psum[n] += __shfl_xor(psum[n], 16, 64);
      psum[n] += __shfl_xor(psum[n], 32, 64);
    }
    __syncthreads();
    float* ps = (float*)wL;
    if (lane < 16) {
      #pragma unroll
      for (int n=0;n<7;n++) ps[wave*112 + n*16 + l15] = psum[n];
    }
    __syncthreads();
    if (t < D_) {
      float v = ps[t] + ps[112+t] + ps[224+t] + ps[336+t];
      int b = (int)(row0 >> 12);
      atomicAdd(&pooled[b*D_ + t], v);
    }
    // ---- fused head: last-finishing block reduces pooled -> out ----
    __threadfence();
    __shared__ int lastflag;
    if (t == 0) lastflag = (atomicAdd(done, 1) == gridDim.x - 1) ? 1 : 0;
    __syncthreads();
    if (lastflag) {
      __threadfence();
      float* red = (float*)wL;          // reuse LDS
      for (int b=0;b<B_;b++){
        float v = 0.f;
        if (t < D_) {
          float pv = atomicAdd(&pooled[b*D_+t], 0.f);   // coherent read
          float xs = xs2acc[b*D_+t] + h2_b[t];
          xs = (xs>0.f)? xs : 0.01f*xs;
          v = (0.5f*xs + (0.5f/IN_DIM_)*pv) * dec_w[t];
        }
        if (t < 128) red[t] = v;
        __syncthreads();
        for (int off=64; off; off>>=1){
          if (t < off) red[t] += red[t+off];
          __syncthreads();
        }
        if (t==0) out[b] = red[0] + dec_b[0];
        __syncthreads();
      }
    }
  } else {
    #pragma unroll
    for (int r=0;r<4;r++) {
      float s = sum[r], s2 = sum2[r];
      #pragma unroll
      for (int m=1;m<16;m<<=1) { s += __shfl_xor(s, m, 16); s2 += __shfl_xor(s2, m, 16); }
      sum[r] = s; sum2[r] = s2;
    }
    #pragma unroll
    for (int n=0;n<7;n++) {
      int col = n*16 + l15;
      float g  = (col < D_) ? lng[col] : 0.f;
      float be = (col < D_) ? lnb[col] : 0.f;
      #pragma unroll
      for (int r=0;r<4;r++) {
        float mu = sum[r]*(1.f/D_);
        float var = sum2[r]*(1.f/D_) - mu*mu;
        float rstd = rsqrtf(var + 1e-5f);
        float hv = fmaxf(fmaf((x_[n][r]-mu)*rstd, g, be), 0.f);
        if (col >= D_) hv = 0.f;
        *(__half*)(hnb + (rbase + r)*256 + 2*col) = __float2half(hv);
        *(unsigned char*)(hnb8 + (rbase + r)*128 + col) = f2fp8(hv);
      }
    }
    {
      int col = 112 + l15;
      __half zh = __float2half(0.f);
      #pragma unroll
      for (int r=0;r<4;r++) {
        *(__half*)(hnb + (rbase + r)*256 + 2*col) = zh;
        *(unsigned char*)(hnb8 + (rbase + r)*128 + col) = 0;
      }
    }
  }
}

extern "C" void kernel_launch(void* const* d_in, const int* in_sizes, int n_in,
                              void* d_out, int out_size, void* d_ws, size_t ws_size,
                              hipStream_t stream) {
  const float* x      = (const float*)d_in[0];
  const int*   eidx   = (const int*)d_in[1];
  const float* enc_w  = (const float*)d_in[3];
  const float* enc_b  = (const float*)d_in[4];
  const float* h1_w   = (const float*)d_in[5];
  const float* h1_b   = (const float*)d_in[6];
  const float* h2_w   = (const float*)d_in[7];
  const float* h2_b   = (const float*)d_in[8];
  const float* ln_g   = (const float*)d_in[9];
  const float* ln_b   = (const float*)d_in[10];
  const float* w1     = (const float*)d_in[11];
  const float* b1     = (const float*)d_in[12];
  const float* bn_g   = (const float*)d_in[13];
  const float* bn_b   = (const float*)d_in[14];
  const float* w2     = (const float*)d_in[15];
  const float* b2     = (const float*)d_in[16];
  const float* dec_w  = (const float*)d_in[17];
  const float* dec_b  = (const float*)d_in[18];
  float* out = (float*)d_out;

  char* ws = (char*)d_ws;
  size_t off = 0;
  auto alloc = [&](size_t bytes)->char* {
    char* p = ws + off;
    off += (bytes + 255) & ~(size_t)255;
    return p;
  };
  __half* h     = (__half*)alloc((size_t)N_*112*2);          // 14.7 MB
  char*  hnb    = alloc((size_t)N_*256);                     // 16.8 MB (fp16 self term)
  char*  hnb8   = alloc((size_t)N_*128);                     //  8.4 MB (fp8 gathers)
  char*  z8     = alloc((size_t)N_*224);                     // 14.7 MB ([N][224] fp8)
  unsigned* u   = (unsigned*)alloc((size_t)N_*64*4);         // 16.8 MB ([N][128] bf16)
  __hip_bfloat16* w1T = (__hip_bfloat16*)alloc((size_t)L_*224*128*2);
  __hip_bfloat16* w2T = (__hip_bfloat16*)alloc((size_t)L_*112*224*2);
  // zero-block: xs1, xs2, pooled, deg, cnt, hist, done -> ONE memset
  size_t zbsz = 64000 + 6400 + 6400 + (size_t)N_*4 + (size_t)N_*4 + 1024 + 256;
  char* zb = alloc(zbsz);
  float* xs1    = (float*)zb;
  float* xs2    = (float*)(zb + 64000);
  float* pooled = (float*)(zb + 64000 + 6400);
  int* deg      = (int*)(zb + 64000 + 6400 + 6400);
  int* cnt      = (int*)(zb + 64000 + 6400 + 6400 + (size_t)N_*4);
  int* hist     = (int*)(zb + 64000 + 6400 + 6400 + (size_t)N_*8);
  int* done     = (int*)(zb + 64000 + 6400 + 6400 + (size_t)N_*8 + 1024);
  int* row_start  = (int*)alloc((N_+1)*4);
  int* sorted_src = (int*)alloc((size_t)E_*4);
  int* order      = (int*)alloc((size_t)N_*4);
  int* binoff     = (int*)alloc(1024);
  int* bincnt     = (int*)alloc(1024);
  float* stats    = (float*)alloc(256);

  const int* srcs = eidx;
  const int* dsts = eidx + E_;

  hipMemsetAsync(zb, 0, zbsz, stream);

  enc_stats_kernel<<<1, 128, 0, stream>>>(enc_w, enc_b, stats);
  setup_kernel<<<SETUP_BLKS_, 256, 0, stream>>>(x, enc_w, enc_b, ln_g, ln_b, stats,
                                                h, hnb, hnb8,
                                                dsts, deg, h1_w, xs1, w1, w2, w1T, w2T);
  stage2_kernel<<<9, 1024, 0, stream>>>(deg, row_start, xs1, h1_b, h2_w, xs2, hist);
  binscan_kernel<<<1, 256, 0, stream>>>(hist, binoff, bincnt);
  scatter_kernel<<<2048+256, 256, 0, stream>>>(srcs, dsts, row_start, cnt, sorted_src,
                                               deg, binoff, bincnt, order);

  for (int i=0;i<L_;i++){
    agg_kernel<<<N_/8, 256, 0, stream>>>(hnb, hnb8, row_start, sorted_src, order, u);
    gemm1_kernel<<<(N_/64)*2, 256, 0, stream>>>((const char*)u,
                                                w1T + (size_t)i*224*128, b1 + i*H_,
                                                bn_g + i*H_, bn_b + i*H_, z8);
    if (i < L_-1) {
      gemm2_kernel<0><<<N_/64, 256, 0, stream>>>(z8, w2T + (size_t)i*112*224, b2 + i*D_,
                                                 h, ln_g + (i+1)*D_, ln_b + (i+1)*D_,
                                                 hnb, hnb8, pooled, done,
                                                 nullptr, nullptr, nullptr, nullptr, nullptr);
    } else {
      gemm2_kernel<1><<<N_/64, 256, 0, stream>>>(z8, w2T + (size_t)i*112*224, b2 + i*D_,
                                                 h, nullptr, nullptr, hnb, hnb8, pooled, done,
                                                 xs2, h2_b, dec_w, dec_b, out);
    }
  }
}

// Round 19
// 394.872 us; speedup vs baseline: 1.1502x; 1.1502x over previous
//
#include <hip/hip_runtime.h>
#include <hip/hip_bf16.h>
#include <hip/hip_fp16.h>
#include <math.h>

#define B_ 16
#define IN_DIM_ 4096
#define D_ 100
#define H_ 200
#define L_ 4
#define N_ (B_*IN_DIM_)     // 65536
#define E_ (8*B_*IN_DIM_)   // 524288
#define EPS_ 1e-7f

typedef __attribute__((ext_vector_type(8))) short bf16x8s;  // 8 bf16 (4 VGPRs)
typedef __attribute__((ext_vector_type(4))) float f32x4;

__device__ inline unsigned pack_bf16x2(float a, float b){
  __hip_bfloat16 x = __float2bfloat16(a), y = __float2bfloat16(b);
  unsigned short ux = *(unsigned short*)&x, uy = *(unsigned short*)&y;
  return (unsigned)ux | ((unsigned)uy << 16);
}
__device__ inline __half2 u2h(unsigned v){ return *(__half2*)&v; }

// fp8 e4m3 (OCP on gfx950) encode via HW cvt
__device__ inline unsigned char f2fp8(float v){
  unsigned p = __builtin_amdgcn_cvt_pk_fp8_f32(v, 0.f, 0u, false);
  return (unsigned char)(p & 0xFF);
}

// ====== enc LN closed-form stats: h=x*w+b (rank-1+bias) => 5 scalars ========
__global__ void enc_stats_kernel(const float* __restrict__ enc_w,
                                 const float* __restrict__ enc_b,
                                 float* __restrict__ stats) {
  __shared__ float sw[128], sb[128], sww[128], swb[128], sbb[128];
  int t = threadIdx.x;
  float w=0.f, b=0.f;
  if (t < D_){ w = enc_w[t]; b = enc_b[t]; }
  sw[t]=w; sb[t]=b; sww[t]=w*w; swb[t]=w*b; sbb[t]=b*b;
  __syncthreads();
  for (int off=64; off; off>>=1){
    if (t<off){ sw[t]+=sw[t+off]; sb[t]+=sb[t+off]; sww[t]+=sww[t+off];
                swb[t]+=swb[t+off]; sbb[t]+=sbb[t+off]; }
    __syncthreads();
  }
  if (t==0){
    float mw = sw[0]*(1.f/D_), mb = sb[0]*(1.f/D_);
    stats[0]=mw; stats[1]=mb;
    stats[2]=sww[0]*(1.f/D_) - mw*mw;      // Var_w
    stats[3]=swb[0]*(1.f/D_) - mw*mb;      // Cov_wb
    stats[4]=sbb[0]*(1.f/D_) - mb*mb;      // Var_b
  }
}

// ================= merged setup: dense1 | enc_ln | deg | prep ================
#define D1_BLKS_   512
#define ENC_BLKS_  2048
#define DEG_BLKS_  2048
#define PREP_BLKS_ 448
#define SETUP_BLKS_ (D1_BLKS_+ENC_BLKS_+DEG_BLKS_+PREP_BLKS_)

__global__ void setup_kernel(const float* __restrict__ x, const float* __restrict__ enc_w,
                             const float* __restrict__ enc_b, const float* __restrict__ g0,
                             const float* __restrict__ b0, const float* __restrict__ stats,
                             __half* __restrict__ h, char* __restrict__ hnb,
                             char* __restrict__ hnb8,
                             const int* __restrict__ dsts, int* __restrict__ deg,
                             const float* __restrict__ h1_w, float* __restrict__ xs1acc,
                             const float* __restrict__ w1, const float* __restrict__ w2,
                             __hip_bfloat16* __restrict__ w1T, __hip_bfloat16* __restrict__ w2T) {
  __shared__ float xl[16][32];    // 2KB (dense1 only)
  int bid = blockIdx.x;
  int t = threadIdx.x;
  if (bid < D1_BLKS_) {
    int bx = bid & 3, by = bid >> 2;
    int k0 = by * 32;
    for (int i = t; i < 16*32; i += 256) {
      int b = i >> 5, kk = i & 31;
      xl[b][kk] = x[b*IN_DIM_ + k0 + kk];
    }
    __syncthreads();
    int c = bx*256 + t;
    if (c >= 1000) return;
    float acc[B_];
    #pragma unroll
    for (int b=0;b<B_;b++) acc[b]=0.f;
    #pragma unroll 4
    for (int kk=0; kk<32; kk++) {
      float w = h1_w[(size_t)(k0+kk)*1000 + c];
      #pragma unroll
      for (int b=0;b<B_;b++) acc[b] += xl[b][kk]*w;
    }
    #pragma unroll
    for (int b=0;b<B_;b++) atomicAdd(&xs1acc[b*1000+c], acc[b]);
  } else if (bid < D1_BLKS_+ENC_BLKS_) {
    int eb = bid - D1_BLKS_;
    int wave = t >> 6, lane = t & 63;
    int base = eb*32 + wave*8;              // this wave's 8 consecutive nodes
    float mw = stats[0], mb = stats[1], vw = stats[2], cwb = stats[3], vb = stats[4];
    float xv = 0.f;
    if (lane < 8) xv = x[base + lane];
    int c0 = 2*lane, c1 = c0+1;
    bool v = c0 < D_;
    float ew0=0.f, ew1=0.f, ebv0=0.f, ebv1=0.f, gg0=0.f, gg1=0.f, bv0=0.f, bv1=0.f;
    if (v) { ew0=enc_w[c0]; ew1=enc_w[c1]; ebv0=enc_b[c0]; ebv1=enc_b[c1];
             gg0=g0[c0]; gg1=g0[c1]; bv0=b0[c0]; bv1=b0[c1]; }
    #pragma unroll
    for (int it=0; it<8; ++it) {
      int wid = base + it;
      float xn = __shfl(xv, it, 64);
      float mu = fmaf(xn, mw, mb);
      float var = fmaf(xn*xn, vw, fmaf(2.f*xn, cwb, vb));
      float rstd = rsqrtf(var + 1e-5f);
      float h0 = fmaf(xn, ew0, ebv0);
      float h1 = fmaf(xn, ew1, ebv1);
      if (c0 < 112) *(__half2*)&h[(size_t)wid*112 + c0] = __floats2half2_rn(h0, h1);
      float n0 = v? fmaxf(fmaf((h0-mu)*rstd, gg0, bv0), 0.f) : 0.f;
      float n1 = v? fmaxf(fmaf((h1-mu)*rstd, gg1, bv1), 0.f) : 0.f;
      *(__half2*)(hnb + (size_t)wid*256 + 4*lane) = __floats2half2_rn(n0, n1);
      unsigned short p8 = (unsigned short)f2fp8(n0) | ((unsigned short)f2fp8(n1) << 8);
      *(unsigned short*)(hnb8 + (size_t)wid*128 + c0) = p8;
    }
  } else if (bid < D1_BLKS_+ENC_BLKS_+DEG_BLKS_) {
    int e = (bid - (D1_BLKS_+ENC_BLKS_))*256 + t;
    if (e < E_) atomicAdd(&deg[dsts[e]], 1);
  } else {
    int idx = (bid - (D1_BLKS_+ENC_BLKS_+DEG_BLKS_))*256 + t;
    if (idx < L_*224*128) {
      int l = idx / (224*128);
      int rem = idx % (224*128);
      int col = rem / 128, k = rem % 128;
      float v = (col < H_ && k < D_) ? w1[(l*D_ + k)*H_ + col] : 0.f;
      w1T[idx] = __float2bfloat16(v);
    }
    if (idx < L_*112*224) {
      int l = idx / (112*224);
      int rem = idx % (112*224);
      int col = rem / 224, k = rem % 224;
      float v = (col < D_ && k < H_) ? w2[(l*H_ + k)*D_ + col] : 0.f;
      w2T[idx] = __float2bfloat16(v);
    }
  }
}

// ====== stage2: scan (blk 0) | dense2 (blk 1-4) | degree hist (blk 5-8) =====
__global__ void stage2_kernel(const int* __restrict__ deg, int* __restrict__ row_start,
                              const float* __restrict__ xs1acc, const float* __restrict__ h1_b,
                              const float* __restrict__ h2_w, float* __restrict__ xs2acc,
                              int* __restrict__ hist) {
  __shared__ int sums[1024];
  int t = threadIdx.x;
  int bid = blockIdx.x;
  if (bid == 0) {
    int base = t*64;
    int s = 0;
    for (int j=0;j<64;j++) s += deg[base+j];
    sums[t] = s;
    __syncthreads();
    for (int off=1; off<1024; off<<=1){
      int add = (t>=off)? sums[t-off] : 0;
      __syncthreads();
      sums[t] += add;
      __syncthreads();
    }
    int excl = (t==0)? 0 : sums[t-1];
    int run = excl;
    for (int j=0;j<64;j++){ row_start[base+j] = run; run += deg[base+j]; }
    if (t==1023) row_start[N_] = run;
  } else if (bid <= 4) {
    int T = (bid-1)*1024 + t;
    if (T >= 100*40) return;
    int c = T % 100, kc = T / 100;
    int k0 = kc*25;
    float acc[B_];
    #pragma unroll
    for (int b=0;b<B_;b++) acc[b]=0.f;
    for (int kk=0;kk<25;kk++){
      int k = k0+kk;
      float w = h2_w[k*100 + c];
      float bk = h1_b[k];
      #pragma unroll
      for (int b=0;b<B_;b++){
        float m = xs1acc[b*1000+k] + bk;
        m = (m>0.f)? m : 0.01f*m;
        acc[b] += m*w;
      }
    }
    #pragma unroll
    for (int b=0;b<B_;b++) atomicAdd(&xs2acc[b*100+c], acc[b]);
  } else {
    __shared__ int lh[256];
    if (t < 256) lh[t] = 0;
    __syncthreads();
    int base = (bid-5)*16384;
    for (int n = base + t; n < base + 16384; n += 1024) {
      int d = deg[n]; if (d > 255) d = 255;
      atomicAdd(&lh[d], 1);
    }
    __syncthreads();
    if (t < 256 && lh[t] > 0) atomicAdd(&hist[t], lh[t]);
  }
}

// ====== binscan: exclusive prefix over 256 degree bins; zero bincnt =========
__global__ void binscan_kernel(const int* __restrict__ hist, int* __restrict__ binoff,
                               int* __restrict__ bincnt) {
  __shared__ int s[256];
  int t = threadIdx.x;
  int hv = hist[t];
  s[t] = hv;
  __syncthreads();
  for (int off=1; off<256; off<<=1){
    int v = (t>=off)? s[t-off] : 0;
    __syncthreads();
    s[t] += v;
    __syncthreads();
  }
  binoff[t] = s[t] - hv;   // exclusive prefix
  bincnt[t] = 0;
}

// ====== scatter: edges (blk<2048) | node order by degree (blk>=2048) ========
__global__ void scatter_kernel(const int* __restrict__ srcs, const int* __restrict__ dst,
                               const int* __restrict__ row_start, int* __restrict__ cnt,
                               int* __restrict__ sorted_src,
                               const int* __restrict__ deg, const int* __restrict__ binoff,
                               int* __restrict__ bincnt, int* __restrict__ order) {
  int bid = blockIdx.x;
  int t = threadIdx.x;
  if (bid < 2048) {
    int e = bid*256 + t;
    int d = dst[e];
    int p = row_start[d] + atomicAdd(&cnt[d], 1);
    sorted_src[p] = srcs[e];
  } else {
    __shared__ int lh[256], lbase[256];
    int n = (bid-2048)*256 + t;
    int d = deg[n]; int b = (d > 255) ? 255 : d;
    lh[t] = 0;
    __syncthreads();
    int myrank = atomicAdd(&lh[b], 1);
    __syncthreads();
    lbase[t] = (lh[t] > 0) ? atomicAdd(&bincnt[t], lh[t]) : 0;
    __syncthreads();
    order[binoff[b] + lbase[b] + myrank] = n;
  }
}

// ---------------- softmax aggregation: 2 nodes/wave, fp8, degree-sorted -----
__global__ void agg_kernel(const char* __restrict__ hnb, const char* __restrict__ hnb8,
                           const int* __restrict__ row_start,
                           const int* __restrict__ sorted_src,
                           const int* __restrict__ order, unsigned* __restrict__ u) {
  int gw = (blockIdx.x*256 + threadIdx.x) >> 6;   // wave id: 0..N/2-1
  int lane = threadIdx.x & 63;
  int lpos = lane & 31;
  int gbase = lane & 32;                          // 0 or 32: group base lane
  int node = order[gw*2 + (lane >> 5)];
  int beg = row_start[node];
  int deg = row_start[node+1] - beg;
  int dother = __shfl_xor(deg, 32, 64);           // other group's (uniform) deg
  int mdeg = deg > dother ? deg : dother;
  const char* lanep8 = hnb8 + 4*lpos;
  float s0=0.f,s1=0.f,s2=0.f,s3=0.f, w0=0.f,w1=0.f,w2=0.f,w3=0.f;

#define CONSUME_(R) { \
    float v0=__builtin_amdgcn_cvt_f32_fp8(R,0)+EPS_; \
    float v1=__builtin_amdgcn_cvt_f32_fp8(R,1)+EPS_; \
    float v2=__builtin_amdgcn_cvt_f32_fp8(R,2)+EPS_; \
    float v3=__builtin_amdgcn_cvt_f32_fp8(R,3)+EPS_; \
    float e0=__expf(v0), e1=__expf(v1), e2=__expf(v2), e3=__expf(v3); \
    s0+=e0; w0=fmaf(e0,v0,w0); s1+=e1; w1=fmaf(e1,v1,w1); \
    s2+=e2; w2=fmaf(e2,v2,w2); s3+=e3; w3=fmaf(e3,v3,w3); }

  for (int cb=0; cb<mdeg; cb+=32){
    int cidx = (cb + lpos < deg) ? sorted_src[beg + cb + lpos] : 0;
    int cnt = mdeg - cb; if (cnt > 32) cnt = 32;          // wave-uniform
    int grem = deg - cb;                                   // per-group remaining
    int glim = grem < cnt ? grem : cnt; if (glim < 0) glim = 0;
    unsigned r0=0, r1=0, r2=0, r3=0;
    if (0 < glim) r0 = *(const unsigned*)(lanep8 + (size_t)__shfl(cidx, gbase+0)*128);
    if (1 < glim) r1 = *(const unsigned*)(lanep8 + (size_t)__shfl(cidx, gbase+1)*128);
    if (2 < glim) r2 = *(const unsigned*)(lanep8 + (size_t)__shfl(cidx, gbase+2)*128);
    if (3 < glim) r3 = *(const unsigned*)(lanep8 + (size_t)__shfl(cidx, gbase+3)*128);
    for (int j=0; j<cnt; j+=4){
      unsigned n0=0, n1=0, n2=0, n3=0;
      if (j+4 < glim) n0 = *(const unsigned*)(lanep8 + (size_t)__shfl(cidx, gbase+j+4)*128);
      if (j+5 < glim) n1 = *(const unsigned*)(lanep8 + (size_t)__shfl(cidx, gbase+j+5)*128);
      if (j+6 < glim) n2 = *(const unsigned*)(lanep8 + (size_t)__shfl(cidx, gbase+j+6)*128);
      if (j+7 < glim) n3 = *(const unsigned*)(lanep8 + (size_t)__shfl(cidx, gbase+j+7)*128);
      if (j   < glim) CONSUME_(r0);
      if (j+1 < glim) CONSUME_(r1);
      if (j+2 < glim) CONSUME_(r2);
      if (j+3 < glim) CONSUME_(r3);
      r0=n0; r1=n1; r2=n2; r3=n3;
    }
  }
#undef CONSUME_

  uint2 own = *(const uint2*)(hnb + (size_t)node*256 + 8*lpos);
  __half2 oa = u2h(own.x), ob = u2h(own.y);
  float u0 = ((deg>0)? w0/s0 : 0.f) + __low2float(oa);
  float u1 = ((deg>0)? w1/s1 : 0.f) + __high2float(oa);
  float u2 = ((deg>0)? w2/s2 : 0.f) + __low2float(ob);
  float u3 = ((deg>0)? w3/s3 : 0.f) + __high2float(ob);
  if (lpos >= 25) { u0=0.f; u1=0.f; u2=0.f; u3=0.f; }   // zero K-pad cols 100..127
  uint2 outv; outv.x = pack_bf16x2(u0,u1); outv.y = pack_bf16x2(u2,u3);
  *(uint2*)((char*)u + (size_t)node*256 + 8*lpos) = outv;
}

// ---------------- GEMM1: weights-only LDS, direct-global A, col-half split --
__global__ __launch_bounds__(256,4) void gemm1_kernel(
    const char* __restrict__ u, const __hip_bfloat16* __restrict__ w1T,
    const float* __restrict__ b1, const float* __restrict__ bng, const float* __restrict__ bnb,
    char* __restrict__ z) {
  __shared__ __align__(16) char wL[112*272];    // 30464 B
  int bid = blockIdx.x;
  int half = bid & 1;
  size_t row0 = (size_t)(bid >> 1) * 64;
  int t = threadIdx.x;
  const char* wg = (const char*)w1T + (size_t)half*112*256;
  #pragma unroll
  for (int c = t; c < 1792; c += 256) {
    int r = c >> 4, sb = (c & 15) << 4;
    *(float4*)(wL + r*272 + sb) = *(const float4*)(wg + (size_t)r*256 + sb);
  }
  __syncthreads();
  int wave = t >> 6, lane = t & 63;
  int l15 = lane & 15;
  int kgb = (lane >> 4) << 4;
  int ar = wave*16 + l15;
  bf16x8s a[4];
  #pragma unroll
  for (int ks=0; ks<4; ks++)
    a[ks] = *(const bf16x8s*)(u + (row0 + ar)*256 + ks*64 + kgb);
  f32x4 acc[7];
  #pragma unroll
  for (int n=0;n<7;n++) acc[n] = (f32x4){0.f,0.f,0.f,0.f};
  #pragma unroll
  for (int ks=0; ks<4; ks++) {
    int kb = ks*64 + kgb;
    #pragma unroll
    for (int n=0;n<7;n++) {
      bf16x8s b = *(const bf16x8s*)(wL + (n*16 + l15)*272 + kb);
      acc[n] = __builtin_amdgcn_mfma_f32_16x16x32_bf16(a[ks], b, acc[n], 0, 0, 0);
    }
  }
  size_t rbase = row0 + wave*16 + ((lane>>4)<<2);
  #pragma unroll
  for (int n=0;n<7;n++) {
    int col = half*112 + n*16 + l15;
    float bias = (col < H_) ? b1[col] : 0.f;
    float g    = (col < H_) ? bng[col] : 0.f;
    float bb   = (col < H_) ? bnb[col] : 0.f;
    #pragma unroll
    for (int r=0;r<4;r++) {
      float v = fmaxf((acc[n][r] + bias)*g + bb, 0.f);
      if (col >= H_) v = 0.f;
      *(__hip_bfloat16*)(z + (rbase + r)*448 + 2*col) = __float2bfloat16(v);
    }
  }
}

// ---------------- GEMM2: weights-only LDS, direct-global A ------------------
template<int LAST>
__global__ __launch_bounds__(256,3) void gemm2_kernel(
    const char* __restrict__ z, const __hip_bfloat16* __restrict__ w2T,
    const float* __restrict__ b2, __half* __restrict__ h,
    const float* __restrict__ lng, const float* __restrict__ lnb,
    char* __restrict__ hnb, char* __restrict__ hnb8, float* __restrict__ pooled) {
  __shared__ __align__(16) char wL[112*464];    // 51968 B
  int t = threadIdx.x;
  size_t row0 = (size_t)blockIdx.x * 64;
  const char* wg = (const char*)w2T;
  for (int c = t; c < 3136; c += 256) {
    int r = c / 28, sb = (c - r*28) << 4;
    *(float4*)(wL + r*464 + sb) = *(const float4*)(wg + (size_t)r*448 + sb);
  }
  __syncthreads();
  int wave = t >> 6, lane = t & 63;
  int l15 = lane & 15;
  int kgb = (lane >> 4) << 4;
  int ar = wave*16 + l15;
  bf16x8s a[7];
  #pragma unroll
  for (int ks=0; ks<7; ks++)
    a[ks] = *(const bf16x8s*)(z + (row0 + ar)*448 + ks*64 + kgb);
  f32x4 acc[7];
  #pragma unroll
  for (int n=0;n<7;n++) acc[n] = (f32x4){0.f,0.f,0.f,0.f};
  #pragma unroll
  for (int ks=0; ks<7; ks++) {
    int kb = ks*64 + kgb;
    #pragma unroll
    for (int n=0;n<7;n++) {
      bf16x8s b = *(const bf16x8s*)(wL + (n*16 + l15)*464 + kb);
      acc[n] = __builtin_amdgcn_mfma_f32_16x16x32_bf16(a[ks], b, acc[n], 0, 0, 0);
    }
  }
  size_t rbase = row0 + wave*16 + ((lane>>4)<<2);

  float x_[7][4];
  float sum[4]  = {0,0,0,0};
  float sum2[4] = {0,0,0,0};
  float psum[7] = {0,0,0,0,0,0,0};
  #pragma unroll
  for (int n=0;n<7;n++) {
    int col = n*16 + l15;
    bool valid = col < D_;
    float bias = valid ? b2[col] : 0.f;
    #pragma unroll
    for (int r=0;r<4;r++) {
      float xv = 0.f;
      if (valid) xv = acc[n][r] + bias + __half2float(h[(rbase + r)*112 + col]);
      x_[n][r] = xv;
      if (LAST) {
        psum[n] += xv;
      } else {
        sum[r] += xv; sum2[r] += xv*xv;
        if (valid) h[(rbase + r)*112 + col] = __float2half(xv);
      }
    }
  }

  if (LAST) {
    #pragma unroll
    for (int n=0;n<7;n++) {
      psum[n] += __shfl_xor(psum[n], 16, 64);
      psum[n] += __shfl_xor(psum[n], 32, 64);
    }
    __syncthreads();
    float* ps = (float*)wL;
    if (lane < 16) {
      #pragma unroll
      for (int n=0;n<7;n++) ps[wave*112 + n*16 + l15] = psum[n];
    }
    __syncthreads();
    if (t < D_) {
      float v = ps[t] + ps[112+t] + ps[224+t] + ps[336+t];
      int b = (int)(row0 >> 12);
      atomicAdd(&pooled[b*D_ + t], v);
    }
  } else {
    #pragma unroll
    for (int r=0;r<4;r++) {
      float s = sum[r], s2 = sum2[r];
      #pragma unroll
      for (int m=1;m<16;m<<=1) { s += __shfl_xor(s, m, 16); s2 += __shfl_xor(s2, m, 16); }
      sum[r] = s; sum2[r] = s2;
    }
    #pragma unroll
    for (int n=0;n<7;n++) {
      int col = n*16 + l15;
      float g  = (col < D_) ? lng[col] : 0.f;
      float be = (col < D_) ? lnb[col] : 0.f;
      #pragma unroll
      for (int r=0;r<4;r++) {
        float mu = sum[r]*(1.f/D_);
        float var = sum2[r]*(1.f/D_) - mu*mu;
        float rstd = rsqrtf(var + 1e-5f);
        float hv = fmaxf(fmaf((x_[n][r]-mu)*rstd, g, be), 0.f);
        if (col >= D_) hv = 0.f;
        *(__half*)(hnb + (rbase + r)*256 + 2*col) = __float2half(hv);
        *(unsigned char*)(hnb8 + (rbase + r)*128 + col) = f2fp8(hv);
      }
    }
    {
      int col = 112 + l15;
      __half zh = __float2half(0.f);
      #pragma unroll
      for (int r=0;r<4;r++) {
        *(__half*)(hnb + (rbase + r)*256 + 2*col) = zh;
        *(unsigned char*)(hnb8 + (rbase + r)*128 + col) = 0;
      }
    }
  }
}

// ---------------- head (dense2 bias+leaky folded in) ----------------
__global__ void final_kernel(const float* __restrict__ xs2acc, const float* __restrict__ h2_b,
                             const float* __restrict__ pooled,
                             const float* __restrict__ dec_w, const float* __restrict__ dec_b,
                             float* __restrict__ out) {
  __shared__ float red[128];
  int t = threadIdx.x;
  for (int b=0;b<B_;b++){
    float v = 0.f;
    if (t < D_) {
      float xs = xs2acc[b*D_+t] + h2_b[t];
      xs = (xs>0.f)? xs : 0.01f*xs;
      v = (0.5f*xs + (0.5f/IN_DIM_)*pooled[b*D_+t]) * dec_w[t];
    }
    red[t] = v;
    __syncthreads();
    for (int off=64; off; off>>=1){
      if (t < off) red[t] += red[t+off];
      __syncthreads();
    }
    if (t==0) out[b] = red[0] + dec_b[0];
    __syncthreads();
  }
}

extern "C" void kernel_launch(void* const* d_in, const int* in_sizes, int n_in,
                              void* d_out, int out_size, void* d_ws, size_t ws_size,
                              hipStream_t stream) {
  const float* x      = (const float*)d_in[0];
  const int*   eidx   = (const int*)d_in[1];
  const float* enc_w  = (const float*)d_in[3];
  const float* enc_b  = (const float*)d_in[4];
  const float* h1_w   = (const float*)d_in[5];
  const float* h1_b   = (const float*)d_in[6];
  const float* h2_w   = (const float*)d_in[7];
  const float* h2_b   = (const float*)d_in[8];
  const float* ln_g   = (const float*)d_in[9];
  const float* ln_b   = (const float*)d_in[10];
  const float* w1     = (const float*)d_in[11];
  const float* b1     = (const float*)d_in[12];
  const float* bn_g   = (const float*)d_in[13];
  const float* bn_b   = (const float*)d_in[14];
  const float* w2     = (const float*)d_in[15];
  const float* b2     = (const float*)d_in[16];
  const float* dec_w  = (const float*)d_in[17];
  const float* dec_b  = (const float*)d_in[18];
  float* out = (float*)d_out;

  char* ws = (char*)d_ws;
  size_t off = 0;
  auto alloc = [&](size_t bytes)->char* {
    char* p = ws + off;
    off += (bytes + 255) & ~(size_t)255;
    return p;
  };
  __half* h     = (__half*)alloc((size_t)N_*112*2);          // 14.7 MB
  char*  hnb    = alloc((size_t)N_*256);                     // 16.8 MB (fp16 self term)
  char*  hnb8   = alloc((size_t)N_*128);                     //  8.4 MB (fp8 gathers)
  char*  z      = alloc((size_t)N_*448);                     // 29.4 MB ([N][224] bf16)
  unsigned* u   = (unsigned*)alloc((size_t)N_*64*4);         // 16.8 MB ([N][128] bf16)
  __hip_bfloat16* w1T = (__hip_bfloat16*)alloc((size_t)L_*224*128*2);
  __hip_bfloat16* w2T = (__hip_bfloat16*)alloc((size_t)L_*112*224*2);
  // zero-block: xs1, xs2, pooled, deg, cnt, hist contiguous -> ONE memset
  size_t zbsz = 64000 + 6400 + 6400 + (size_t)N_*4 + (size_t)N_*4 + 1024;
  char* zb = alloc(zbsz);
  float* xs1    = (float*)zb;
  float* xs2    = (float*)(zb + 64000);
  float* pooled = (float*)(zb + 64000 + 6400);
  int* deg      = (int*)(zb + 64000 + 6400 + 6400);
  int* cnt      = (int*)(zb + 64000 + 6400 + 6400 + (size_t)N_*4);
  int* hist     = (int*)(zb + 64000 + 6400 + 6400 + (size_t)N_*8);
  int* row_start  = (int*)alloc((N_+1)*4);
  int* sorted_src = (int*)alloc((size_t)E_*4);
  int* order      = (int*)alloc((size_t)N_*4);
  int* binoff     = (int*)alloc(1024);
  int* bincnt     = (int*)alloc(1024);
  float* stats    = (float*)alloc(256);

  const int* srcs = eidx;
  const int* dsts = eidx + E_;

  hipMemsetAsync(zb, 0, zbsz, stream);

  enc_stats_kernel<<<1, 128, 0, stream>>>(enc_w, enc_b, stats);
  setup_kernel<<<SETUP_BLKS_, 256, 0, stream>>>(x, enc_w, enc_b, ln_g, ln_b, stats,
                                                h, hnb, hnb8,
                                                dsts, deg, h1_w, xs1, w1, w2, w1T, w2T);
  stage2_kernel<<<9, 1024, 0, stream>>>(deg, row_start, xs1, h1_b, h2_w, xs2, hist);
  binscan_kernel<<<1, 256, 0, stream>>>(hist, binoff, bincnt);
  scatter_kernel<<<2048+256, 256, 0, stream>>>(srcs, dsts, row_start, cnt, sorted_src,
                                               deg, binoff, bincnt, order);

  for (int i=0;i<L_;i++){
    agg_kernel<<<N_/8, 256, 0, stream>>>(hnb, hnb8, row_start, sorted_src, order, u);
    gemm1_kernel<<<(N_/64)*2, 256, 0, stream>>>((const char*)u,
                                                w1T + (size_t)i*224*128, b1 + i*H_,
                                                bn_g + i*H_, bn_b + i*H_, z);
    if (i < L_-1) {
      gemm2_kernel<0><<<N_/64, 256, 0, stream>>>(z, w2T + (size_t)i*112*224, b2 + i*D_,
                                                 h, ln_g + (i+1)*D_, ln_b + (i+1)*D_,
                                                 hnb, hnb8, pooled);
    } else {
      gemm2_kernel<1><<<N_/64, 256, 0, stream>>>(z, w2T + (size_t)i*112*224, b2 + i*D_,
                                                 h, nullptr, nullptr, hnb, hnb8, pooled);
    }
  }

  final_kernel<<<1, 128, 0, stream>>>(xs2, h2_b, pooled, dec_w, dec_b, out);
}

// Round 20
// 364.960 us; speedup vs baseline: 1.2445x; 1.0820x over previous
//
#include <hip/hip_runtime.h>
#include <hip/hip_bf16.h>
#include <hip/hip_fp16.h>
#include <math.h>

#define B_ 16
#define IN_DIM_ 4096
#define D_ 100
#define H_ 200
#define L_ 4
#define N_ (B_*IN_DIM_)     // 65536
#define E_ (8*B_*IN_DIM_)   // 524288
#define EPS_ 1e-7f

typedef __attribute__((ext_vector_type(8))) short bf16x8s;  // 8 bf16 (4 VGPRs)
typedef __attribute__((ext_vector_type(4))) float f32x4;

__device__ inline unsigned pack_bf16x2(float a, float b){
  __hip_bfloat16 x = __float2bfloat16(a), y = __float2bfloat16(b);
  unsigned short ux = *(unsigned short*)&x, uy = *(unsigned short*)&y;
  return (unsigned)ux | ((unsigned)uy << 16);
}
__device__ inline __half2 u2h(unsigned v){ return *(__half2*)&v; }

// fp8 e4m3 (OCP on gfx950) encode via HW cvt
__device__ inline unsigned char f2fp8(float v){
  unsigned p = __builtin_amdgcn_cvt_pk_fp8_f32(v, 0.f, 0u, false);
  return (unsigned char)(p & 0xFF);
}

// ====== enc LN closed-form stats: h=x*w+b (rank-1+bias) => 5 scalars ========
__global__ void enc_stats_kernel(const float* __restrict__ enc_w,
                                 const float* __restrict__ enc_b,
                                 float* __restrict__ stats) {
  __shared__ float sw[128], sb[128], sww[128], swb[128], sbb[128];
  int t = threadIdx.x;
  float w=0.f, b=0.f;
  if (t < D_){ w = enc_w[t]; b = enc_b[t]; }
  sw[t]=w; sb[t]=b; sww[t]=w*w; swb[t]=w*b; sbb[t]=b*b;
  __syncthreads();
  for (int off=64; off; off>>=1){
    if (t<off){ sw[t]+=sw[t+off]; sb[t]+=sb[t+off]; sww[t]+=sww[t+off];
                swb[t]+=swb[t+off]; sbb[t]+=sbb[t+off]; }
    __syncthreads();
  }
  if (t==0){
    float mw = sw[0]*(1.f/D_), mb = sb[0]*(1.f/D_);
    stats[0]=mw; stats[1]=mb;
    stats[2]=sww[0]*(1.f/D_) - mw*mw;      // Var_w
    stats[3]=swb[0]*(1.f/D_) - mw*mb;      // Cov_wb
    stats[4]=sbb[0]*(1.f/D_) - mb*mb;      // Var_b
  }
}

// ================= merged setup: dense1 | enc_ln | deg | prep ================
#define D1_BLKS_   512
#define ENC_BLKS_  2048
#define DEG_BLKS_  2048
#define PREP_BLKS_ 448
#define SETUP_BLKS_ (D1_BLKS_+ENC_BLKS_+DEG_BLKS_+PREP_BLKS_)

__global__ void setup_kernel(const float* __restrict__ x, const float* __restrict__ enc_w,
                             const float* __restrict__ enc_b, const float* __restrict__ g0,
                             const float* __restrict__ b0, const float* __restrict__ stats,
                             __half* __restrict__ h, char* __restrict__ hnb,
                             char* __restrict__ hnb8,
                             const int* __restrict__ dsts, int* __restrict__ deg,
                             const float* __restrict__ h1_w, float* __restrict__ xs1acc,
                             const float* __restrict__ w1, const float* __restrict__ w2,
                             __hip_bfloat16* __restrict__ w1T, char* __restrict__ w2T8) {
  __shared__ float xl[16][32];    // 2KB (dense1 only)
  int bid = blockIdx.x;
  int t = threadIdx.x;
  if (bid < D1_BLKS_) {
    int bx = bid & 3, by = bid >> 2;
    int k0 = by * 32;
    for (int i = t; i < 16*32; i += 256) {
      int b = i >> 5, kk = i & 31;
      xl[b][kk] = x[b*IN_DIM_ + k0 + kk];
    }
    __syncthreads();
    int c = bx*256 + t;
    if (c >= 1000) return;
    float acc[B_];
    #pragma unroll
    for (int b=0;b<B_;b++) acc[b]=0.f;
    #pragma unroll 4
    for (int kk=0; kk<32; kk++) {
      float w = h1_w[(size_t)(k0+kk)*1000 + c];
      #pragma unroll
      for (int b=0;b<B_;b++) acc[b] += xl[b][kk]*w;
    }
    #pragma unroll
    for (int b=0;b<B_;b++) atomicAdd(&xs1acc[b*1000+c], acc[b]);
  } else if (bid < D1_BLKS_+ENC_BLKS_) {
    int eb = bid - D1_BLKS_;
    int wave = t >> 6, lane = t & 63;
    int base = eb*32 + wave*8;              // this wave's 8 consecutive nodes
    float mw = stats[0], mb = stats[1], vw = stats[2], cwb = stats[3], vb = stats[4];
    float xv = 0.f;
    if (lane < 8) xv = x[base + lane];
    int c0 = 2*lane, c1 = c0+1;
    bool v = c0 < D_;
    float ew0=0.f, ew1=0.f, ebv0=0.f, ebv1=0.f, gg0=0.f, gg1=0.f, bv0=0.f, bv1=0.f;
    if (v) { ew0=enc_w[c0]; ew1=enc_w[c1]; ebv0=enc_b[c0]; ebv1=enc_b[c1];
             gg0=g0[c0]; gg1=g0[c1]; bv0=b0[c0]; bv1=b0[c1]; }
    #pragma unroll
    for (int it=0; it<8; ++it) {
      int wid = base + it;
      float xn = __shfl(xv, it, 64);
      float mu = fmaf(xn, mw, mb);
      float var = fmaf(xn*xn, vw, fmaf(2.f*xn, cwb, vb));
      float rstd = rsqrtf(var + 1e-5f);
      float h0 = fmaf(xn, ew0, ebv0);
      float h1 = fmaf(xn, ew1, ebv1);
      if (c0 < 112) *(__half2*)&h[(size_t)wid*112 + c0] = __floats2half2_rn(h0, h1);
      float n0 = v? fmaxf(fmaf((h0-mu)*rstd, gg0, bv0), 0.f) : 0.f;
      float n1 = v? fmaxf(fmaf((h1-mu)*rstd, gg1, bv1), 0.f) : 0.f;
      *(__half2*)(hnb + (size_t)wid*256 + 4*lane) = __floats2half2_rn(n0, n1);
      unsigned short p8 = (unsigned short)f2fp8(n0) | ((unsigned short)f2fp8(n1) << 8);
      *(unsigned short*)(hnb8 + (size_t)wid*128 + c0) = p8;
    }
  } else if (bid < D1_BLKS_+ENC_BLKS_+DEG_BLKS_) {
    int e = (bid - (D1_BLKS_+ENC_BLKS_))*256 + t;
    if (e < E_) atomicAdd(&deg[dsts[e]], 1);
  } else {
    int idx = (bid - (D1_BLKS_+ENC_BLKS_+DEG_BLKS_))*256 + t;
    if (idx < L_*224*128) {
      int l = idx / (224*128);
      int rem = idx % (224*128);
      int col = rem / 128, k = rem % 128;
      float v = (col < H_ && k < D_) ? w1[(l*D_ + k)*H_ + col] : 0.f;
      w1T[idx] = __float2bfloat16(v);
    }
    if (idx < L_*112*224) {
      int l = idx / (112*224);
      int rem = idx % (112*224);
      int col = rem / 224, k = rem % 224;
      float v = (col < D_ && k < H_) ? w2[(l*H_ + k)*D_ + col] : 0.f;
      w2T8[idx] = f2fp8(v);
    }
  }
}

// ====== stage2: scan (blk 0) | dense2 (blk 1-4) | degree hist (blk 5-8) =====
__global__ void stage2_kernel(const int* __restrict__ deg, int* __restrict__ row_start,
                              const float* __restrict__ xs1acc, const float* __restrict__ h1_b,
                              const float* __restrict__ h2_w, float* __restrict__ xs2acc,
                              int* __restrict__ hist) {
  __shared__ int sums[1024];
  int t = threadIdx.x;
  int bid = blockIdx.x;
  if (bid == 0) {
    int base = t*64;
    int s = 0;
    for (int j=0;j<64;j++) s += deg[base+j];
    sums[t] = s;
    __syncthreads();
    for (int off=1; off<1024; off<<=1){
      int add = (t>=off)? sums[t-off] : 0;
      __syncthreads();
      sums[t] += add;
      __syncthreads();
    }
    int excl = (t==0)? 0 : sums[t-1];
    int run = excl;
    for (int j=0;j<64;j++){ row_start[base+j] = run; run += deg[base+j]; }
    if (t==1023) row_start[N_] = run;
  } else if (bid <= 4) {
    int T = (bid-1)*1024 + t;
    if (T >= 100*40) return;
    int c = T % 100, kc = T / 100;
    int k0 = kc*25;
    float acc[B_];
    #pragma unroll
    for (int b=0;b<B_;b++) acc[b]=0.f;
    for (int kk=0;kk<25;kk++){
      int k = k0+kk;
      float w = h2_w[k*100 + c];
      float bk = h1_b[k];
      #pragma unroll
      for (int b=0;b<B_;b++){
        float m = xs1acc[b*1000+k] + bk;
        m = (m>0.f)? m : 0.01f*m;
        acc[b] += m*w;
      }
    }
    #pragma unroll
    for (int b=0;b<B_;b++) atomicAdd(&xs2acc[b*100+c], acc[b]);
  } else {
    __shared__ int lh[256];
    if (t < 256) lh[t] = 0;
    __syncthreads();
    int base = (bid-5)*16384;
    for (int n = base + t; n < base + 16384; n += 1024) {
      int d = deg[n]; if (d > 255) d = 255;
      atomicAdd(&lh[d], 1);
    }
    __syncthreads();
    if (t < 256 && lh[t] > 0) atomicAdd(&hist[t], lh[t]);
  }
}

// ====== binscan: exclusive prefix over 256 degree bins; zero bincnt =========
__global__ void binscan_kernel(const int* __restrict__ hist, int* __restrict__ binoff,
                               int* __restrict__ bincnt) {
  __shared__ int s[256];
  int t = threadIdx.x;
  int hv = hist[t];
  s[t] = hv;
  __syncthreads();
  for (int off=1; off<256; off<<=1){
    int v = (t>=off)? s[t-off] : 0;
    __syncthreads();
    s[t] += v;
    __syncthreads();
  }
  binoff[t] = s[t] - hv;   // exclusive prefix
  bincnt[t] = 0;
}

// ====== scatter: edges (blk<2048) | node order by degree (blk>=2048) ========
__global__ void scatter_kernel(const int* __restrict__ srcs, const int* __restrict__ dst,
                               const int* __restrict__ row_start, int* __restrict__ cnt,
                               int* __restrict__ sorted_src,
                               const int* __restrict__ deg, const int* __restrict__ binoff,
                               int* __restrict__ bincnt, int* __restrict__ order) {
  int bid = blockIdx.x;
  int t = threadIdx.x;
  if (bid < 2048) {
    int e = bid*256 + t;
    int d = dst[e];
    int p = row_start[d] + atomicAdd(&cnt[d], 1);
    sorted_src[p] = srcs[e];
  } else {
    __shared__ int lh[256], lbase[256];
    int n = (bid-2048)*256 + t;
    int d = deg[n]; int b = (d > 255) ? 255 : d;
    lh[t] = 0;
    __syncthreads();
    int myrank = atomicAdd(&lh[b], 1);
    __syncthreads();
    lbase[t] = (lh[t] > 0) ? atomicAdd(&bincnt[t], lh[t]) : 0;
    __syncthreads();
    order[binoff[b] + lbase[b] + myrank] = n;
  }
}

// ---------------- softmax aggregation: 2 nodes/wave, fp8, degree-sorted -----
__global__ void agg_kernel(const char* __restrict__ hnb, const char* __restrict__ hnb8,
                           const int* __restrict__ row_start,
                           const int* __restrict__ sorted_src,
                           const int* __restrict__ order, unsigned* __restrict__ u) {
  int gw = (blockIdx.x*256 + threadIdx.x) >> 6;   // wave id: 0..N/2-1
  int lane = threadIdx.x & 63;
  int lpos = lane & 31;
  int gbase = lane & 32;                          // 0 or 32: group base lane
  int node = order[gw*2 + (lane >> 5)];
  int beg = row_start[node];
  int deg = row_start[node+1] - beg;
  int dother = __shfl_xor(deg, 32, 64);           // other group's (uniform) deg
  int mdeg = deg > dother ? deg : dother;
  const char* lanep8 = hnb8 + 4*lpos;
  float s0=0.f,s1=0.f,s2=0.f,s3=0.f, w0=0.f,w1=0.f,w2=0.f,w3=0.f;

#define CONSUME_(R) { \
    float v0=__builtin_amdgcn_cvt_f32_fp8(R,0)+EPS_; \
    float v1=__builtin_amdgcn_cvt_f32_fp8(R,1)+EPS_; \
    float v2=__builtin_amdgcn_cvt_f32_fp8(R,2)+EPS_; \
    float v3=__builtin_amdgcn_cvt_f32_fp8(R,3)+EPS_; \
    float e0=__expf(v0), e1=__expf(v1), e2=__expf(v2), e3=__expf(v3); \
    s0+=e0; w0=fmaf(e0,v0,w0); s1+=e1; w1=fmaf(e1,v1,w1); \
    s2+=e2; w2=fmaf(e2,v2,w2); s3+=e3; w3=fmaf(e3,v3,w3); }

  for (int cb=0; cb<mdeg; cb+=32){
    int cidx = (cb + lpos < deg) ? sorted_src[beg + cb + lpos] : 0;
    int cnt = mdeg - cb; if (cnt > 32) cnt = 32;          // wave-uniform
    int grem = deg - cb;                                   // per-group remaining
    int glim = grem < cnt ? grem : cnt; if (glim < 0) glim = 0;
    unsigned r0=0, r1=0, r2=0, r3=0;
    if (0 < glim) r0 = *(const unsigned*)(lanep8 + (size_t)__shfl(cidx, gbase+0)*128);
    if (1 < glim) r1 = *(const unsigned*)(lanep8 + (size_t)__shfl(cidx, gbase+1)*128);
    if (2 < glim) r2 = *(const unsigned*)(lanep8 + (size_t)__shfl(cidx, gbase+2)*128);
    if (3 < glim) r3 = *(const unsigned*)(lanep8 + (size_t)__shfl(cidx, gbase+3)*128);
    for (int j=0; j<cnt; j+=4){
      unsigned n0=0, n1=0, n2=0, n3=0;
      if (j+4 < glim) n0 = *(const unsigned*)(lanep8 + (size_t)__shfl(cidx, gbase+j+4)*128);
      if (j+5 < glim) n1 = *(const unsigned*)(lanep8 + (size_t)__shfl(cidx, gbase+j+5)*128);
      if (j+6 < glim) n2 = *(const unsigned*)(lanep8 + (size_t)__shfl(cidx, gbase+j+6)*128);
      if (j+7 < glim) n3 = *(const unsigned*)(lanep8 + (size_t)__shfl(cidx, gbase+j+7)*128);
      if (j   < glim) CONSUME_(r0);
      if (j+1 < glim) CONSUME_(r1);
      if (j+2 < glim) CONSUME_(r2);
      if (j+3 < glim) CONSUME_(r3);
      r0=n0; r1=n1; r2=n2; r3=n3;
    }
  }
#undef CONSUME_

  uint2 own = *(const uint2*)(hnb + (size_t)node*256 + 8*lpos);
  __half2 oa = u2h(own.x), ob = u2h(own.y);
  float u0 = ((deg>0)? w0/s0 : 0.f) + __low2float(oa);
  float u1 = ((deg>0)? w1/s1 : 0.f) + __high2float(oa);
  float u2 = ((deg>0)? w2/s2 : 0.f) + __low2float(ob);
  float u3 = ((deg>0)? w3/s3 : 0.f) + __high2float(ob);
  if (lpos >= 25) { u0=0.f; u1=0.f; u2=0.f; u3=0.f; }   // zero K-pad cols 100..127
  uint2 outv; outv.x = pack_bf16x2(u0,u1); outv.y = pack_bf16x2(u2,u3);
  *(uint2*)((char*)u + (size_t)node*256 + 8*lpos) = outv;
}

// ---------------- GEMM1: weights-only LDS, direct-global A; z out fp8 -------
__global__ __launch_bounds__(256,4) void gemm1_kernel(
    const char* __restrict__ u, const __hip_bfloat16* __restrict__ w1T,
    const float* __restrict__ b1, const float* __restrict__ bng, const float* __restrict__ bnb,
    char* __restrict__ z8) {
  __shared__ __align__(16) char wL[112*272];    // 30464 B
  int bid = blockIdx.x;
  int half = bid & 1;
  size_t row0 = (size_t)(bid >> 1) * 64;
  int t = threadIdx.x;
  const char* wg = (const char*)w1T + (size_t)half*112*256;
  #pragma unroll
  for (int c = t; c < 1792; c += 256) {
    int r = c >> 4, sb = (c & 15) << 4;
    *(float4*)(wL + r*272 + sb) = *(const float4*)(wg + (size_t)r*256 + sb);
  }
  __syncthreads();
  int wave = t >> 6, lane = t & 63;
  int l15 = lane & 15;
  int kgb = (lane >> 4) << 4;
  int ar = wave*16 + l15;
  bf16x8s a[4];
  #pragma unroll
  for (int ks=0; ks<4; ks++)
    a[ks] = *(const bf16x8s*)(u + (row0 + ar)*256 + ks*64 + kgb);
  f32x4 acc[7];
  #pragma unroll
  for (int n=0;n<7;n++) acc[n] = (f32x4){0.f,0.f,0.f,0.f};
  #pragma unroll
  for (int ks=0; ks<4; ks++) {
    int kb = ks*64 + kgb;
    #pragma unroll
    for (int n=0;n<7;n++) {
      bf16x8s b = *(const bf16x8s*)(wL + (n*16 + l15)*272 + kb);
      acc[n] = __builtin_amdgcn_mfma_f32_16x16x32_bf16(a[ks], b, acc[n], 0, 0, 0);
    }
  }
  size_t rbase = row0 + wave*16 + ((lane>>4)<<2);
  #pragma unroll
  for (int n=0;n<7;n++) {
    int col = half*112 + n*16 + l15;
    float bias = (col < H_) ? b1[col] : 0.f;
    float g    = (col < H_) ? bng[col] : 0.f;
    float bb   = (col < H_) ? bnb[col] : 0.f;
    #pragma unroll
    for (int r=0;r<4;r++) {
      float v = fmaxf((acc[n][r] + bias)*g + bb, 0.f);
      if (col >= H_) v = 0.f;
      *(unsigned char*)(z8 + (rbase + r)*224 + col) = f2fp8(v);
    }
  }
}

// ---------------- GEMM2: fp8 x fp8 MFMA; 26KB LDS (4 blocks/CU) -------------
template<int LAST>
__global__ __launch_bounds__(256,4) void gemm2_kernel(
    const char* __restrict__ z8, const char* __restrict__ w2T8,
    const float* __restrict__ b2, __half* __restrict__ h,
    const float* __restrict__ lng, const float* __restrict__ lnb,
    char* __restrict__ hnb, char* __restrict__ hnb8, float* __restrict__ pooled) {
  __shared__ __align__(16) char wL[112*232];    // 25984 B
  int t = threadIdx.x;
  size_t row0 = (size_t)blockIdx.x * 64;
  const char* wg = w2T8;
  for (int c = t; c < 1568; c += 256) {          // 112 rows x 14 chunks of 16B
    int r = c / 14, sb = (c - r*14) << 4;
    *(float4*)(wL + r*232 + sb) = *(const float4*)(wg + (size_t)r*224 + sb);
  }
  __syncthreads();
  int wave = t >> 6, lane = t & 63;
  int l15 = lane & 15;
  int g8 = (lane >> 4) << 3;      // 8B per K-group (8 fp8)
  int ar = wave*16 + l15;
  // A fragments: direct 8B loads from fp8 z rows (224B)
  long long av[7];
  {
    const char* zrow = z8 + (row0 + ar)*224;
    #pragma unroll
    for (int ks=0; ks<7; ks++)
      av[ks] = *(const long long*)(zrow + ks*32 + g8);
  }
  f32x4 acc[7];
  #pragma unroll
  for (int n=0;n<7;n++) acc[n] = (f32x4){0.f,0.f,0.f,0.f};
  #pragma unroll
  for (int ks=0; ks<7; ks++) {
    int kb = ks*32 + g8;
    #pragma unroll
    for (int n=0;n<7;n++) {
      long long bv = *(const long long*)(wL + (n*16 + l15)*232 + kb);
      acc[n] = __builtin_amdgcn_mfma_f32_16x16x32_fp8_fp8(av[ks], bv, acc[n], 0, 0, 0);
    }
  }
  size_t rbase = row0 + wave*16 + ((lane>>4)<<2);

  float x_[7][4];
  float sum[4]  = {0,0,0,0};
  float sum2[4] = {0,0,0,0};
  float psum[7] = {0,0,0,0,0,0,0};
  #pragma unroll
  for (int n=0;n<7;n++) {
    int col = n*16 + l15;
    bool valid = col < D_;
    float bias = valid ? b2[col] : 0.f;
    #pragma unroll
    for (int r=0;r<4;r++) {
      float xv = 0.f;
      if (valid) xv = acc[n][r] + bias + __half2float(h[(rbase + r)*112 + col]);
      x_[n][r] = xv;
      if (LAST) {
        psum[n] += xv;
      } else {
        sum[r] += xv; sum2[r] += xv*xv;
        if (valid) h[(rbase + r)*112 + col] = __float2half(xv);
      }
    }
  }

  if (LAST) {
    #pragma unroll
    for (int n=0;n<7;n++) {
      psum[n] += __shfl_xor(psum[n], 16, 64);
      psum[n] += __shfl_xor(psum[n], 32, 64);
    }
    __syncthreads();
    float* ps = (float*)wL;
    if (lane < 16) {
      #pragma unroll
      for (int n=0;n<7;n++) ps[wave*112 + n*16 + l15] = psum[n];
    }
    __syncthreads();
    if (t < D_) {
      float v = ps[t] + ps[112+t] + ps[224+t] + ps[336+t];
      int b = (int)(row0 >> 12);
      atomicAdd(&pooled[b*D_ + t], v);
    }
  } else {
    #pragma unroll
    for (int r=0;r<4;r++) {
      float s = sum[r], s2 = sum2[r];
      #pragma unroll
      for (int m=1;m<16;m<<=1) { s += __shfl_xor(s, m, 16); s2 += __shfl_xor(s2, m, 16); }
      sum[r] = s; sum2[r] = s2;
    }
    #pragma unroll
    for (int n=0;n<7;n++) {
      int col = n*16 + l15;
      float g  = (col < D_) ? lng[col] : 0.f;
      float be = (col < D_) ? lnb[col] : 0.f;
      #pragma unroll
      for (int r=0;r<4;r++) {
        float mu = sum[r]*(1.f/D_);
        float var = sum2[r]*(1.f/D_) - mu*mu;
        float rstd = rsqrtf(var + 1e-5f);
        float hv = fmaxf(fmaf((x_[n][r]-mu)*rstd, g, be), 0.f);
        if (col >= D_) hv = 0.f;
        *(__half*)(hnb + (rbase + r)*256 + 2*col) = __float2half(hv);
        *(unsigned char*)(hnb8 + (rbase + r)*128 + col) = f2fp8(hv);
      }
    }
    {
      int col = 112 + l15;
      __half zh = __float2half(0.f);
      #pragma unroll
      for (int r=0;r<4;r++) {
        *(__half*)(hnb + (rbase + r)*256 + 2*col) = zh;
        *(unsigned char*)(hnb8 + (rbase + r)*128 + col) = 0;
      }
    }
  }
}

// ---------------- head (dense2 bias+leaky folded in) ----------------
__global__ void final_kernel(const float* __restrict__ xs2acc, const float* __restrict__ h2_b,
                             const float* __restrict__ pooled,
                             const float* __restrict__ dec_w, const float* __restrict__ dec_b,
                             float* __restrict__ out) {
  __shared__ float red[128];
  int t = threadIdx.x;
  for (int b=0;b<B_;b++){
    float v = 0.f;
    if (t < D_) {
      float xs = xs2acc[b*D_+t] + h2_b[t];
      xs = (xs>0.f)? xs : 0.01f*xs;
      v = (0.5f*xs + (0.5f/IN_DIM_)*pooled[b*D_+t]) * dec_w[t];
    }
    red[t] = v;
    __syncthreads();
    for (int off=64; off; off>>=1){
      if (t < off) red[t] += red[t+off];
      __syncthreads();
    }
    if (t==0) out[b] = red[0] + dec_b[0];
    __syncthreads();
  }
}

extern "C" void kernel_launch(void* const* d_in, const int* in_sizes, int n_in,
                              void* d_out, int out_size, void* d_ws, size_t ws_size,
                              hipStream_t stream) {
  const float* x      = (const float*)d_in[0];
  const int*   eidx   = (const int*)d_in[1];
  const float* enc_w  = (const float*)d_in[3];
  const float* enc_b  = (const float*)d_in[4];
  const float* h1_w   = (const float*)d_in[5];
  const float* h1_b   = (const float*)d_in[6];
  const float* h2_w   = (const float*)d_in[7];
  const float* h2_b   = (const float*)d_in[8];
  const float* ln_g   = (const float*)d_in[9];
  const float* ln_b   = (const float*)d_in[10];
  const float* w1     = (const float*)d_in[11];
  const float* b1     = (const float*)d_in[12];
  const float* bn_g   = (const float*)d_in[13];
  const float* bn_b   = (const float*)d_in[14];
  const float* w2     = (const float*)d_in[15];
  const float* b2     = (const float*)d_in[16];
  const float* dec_w  = (const float*)d_in[17];
  const float* dec_b  = (const float*)d_in[18];
  float* out = (float*)d_out;

  char* ws = (char*)d_ws;
  size_t off = 0;
  auto alloc = [&](size_t bytes)->char* {
    char* p = ws + off;
    off += (bytes + 255) & ~(size_t)255;
    return p;
  };
  __half* h     = (__half*)alloc((size_t)N_*112*2);          // 14.7 MB
  char*  hnb    = alloc((size_t)N_*256);                     // 16.8 MB (fp16 self term)
  char*  hnb8   = alloc((size_t)N_*128);                     //  8.4 MB (fp8 gathers)
  char*  z8     = alloc((size_t)N_*224);                     // 14.7 MB ([N][224] fp8)
  unsigned* u   = (unsigned*)alloc((size_t)N_*64*4);         // 16.8 MB ([N][128] bf16)
  __hip_bfloat16* w1T = (__hip_bfloat16*)alloc((size_t)L_*224*128*2);
  char* w2T8    = alloc((size_t)L_*112*224);                 // fp8 weights
  // zero-block: xs1, xs2, pooled, deg, cnt, hist contiguous -> ONE memset
  size_t zbsz = 64000 + 6400 + 6400 + (size_t)N_*4 + (size_t)N_*4 + 1024;
  char* zb = alloc(zbsz);
  float* xs1    = (float*)zb;
  float* xs2    = (float*)(zb + 64000);
  float* pooled = (float*)(zb + 64000 + 6400);
  int* deg      = (int*)(zb + 64000 + 6400 + 6400);
  int* cnt      = (int*)(zb + 64000 + 6400 + 6400 + (size_t)N_*4);
  int* hist     = (int*)(zb + 64000 + 6400 + 6400 + (size_t)N_*8);
  int* row_start  = (int*)alloc((N_+1)*4);
  int* sorted_src = (int*)alloc((size_t)E_*4);
  int* order      = (int*)alloc((size_t)N_*4);
  int* binoff     = (int*)alloc(1024);
  int* bincnt     = (int*)alloc(1024);
  float* stats    = (float*)alloc(256);

  const int* srcs = eidx;
  const int* dsts = eidx + E_;

  hipMemsetAsync(zb, 0, zbsz, stream);

  enc_stats_kernel<<<1, 128, 0, stream>>>(enc_w, enc_b, stats);
  setup_kernel<<<SETUP_BLKS_, 256, 0, stream>>>(x, enc_w, enc_b, ln_g, ln_b, stats,
                                                h, hnb, hnb8,
                                                dsts, deg, h1_w, xs1, w1, w2, w1T, w2T8);
  stage2_kernel<<<9, 1024, 0, stream>>>(deg, row_start, xs1, h1_b, h2_w, xs2, hist);
  binscan_kernel<<<1, 256, 0, stream>>>(hist, binoff, bincnt);
  scatter_kernel<<<2048+256, 256, 0, stream>>>(srcs, dsts, row_start, cnt, sorted_src,
                                               deg, binoff, bincnt, order);

  for (int i=0;i<L_;i++){
    agg_kernel<<<N_/8, 256, 0, stream>>>(hnb, hnb8, row_start, sorted_src, order, u);
    gemm1_kernel<<<(N_/64)*2, 256, 0, stream>>>((const char*)u,
                                                w1T + (size_t)i*224*128, b1 + i*H_,
                                                bn_g + i*H_, bn_b + i*H_, z8);
    if (i < L_-1) {
      gemm2_kernel<0><<<N_/64, 256, 0, stream>>>(z8, w2T8 + (size_t)i*112*224, b2 + i*D_,
                                                 h, ln_g + (i+1)*D_, ln_b + (i+1)*D_,
                                                 hnb, hnb8, pooled);
    } else {
      gemm2_kernel<1><<<N_/64, 256, 0, stream>>>(z8, w2T8 + (size_t)i*112*224, b2 + i*D_,
                                                 h, nullptr, nullptr, hnb, hnb8, pooled);
    }
  }

  final_kernel<<<1, 128, 0, stream>>>(xs2, h2_b, pooled, dec_w, dec_b, out);
}